// Round 17
// baseline (420.162 us; speedup 1.0000x reference)
//
#include <hip/hip_runtime.h>

typedef __bf16 bf16;
typedef __bf16 bf16x4 __attribute__((ext_vector_type(4)));
typedef __bf16 bf16x8 __attribute__((ext_vector_type(8)));
typedef float f32x4 __attribute__((ext_vector_type(4)));

#define MFMA16(a, b, c) __builtin_amdgcn_mfma_f32_16x16x32_bf16((a), (b), (c), 0, 0, 0)

// global -> LDS DMA, 16B per lane; LDS dest is wave-uniform base + lane*16.
#define GLD16(gp, lp)                                                              \
  __builtin_amdgcn_global_load_lds(                                                \
      (const __attribute__((address_space(1))) unsigned int*)(unsigned long long)(gp), \
      (__attribute__((address_space(3))) unsigned int*)(unsigned long long)(lp), 16, 0, 0)

// B=256, T=320, C=1024, H=64;  M = B*T = 81920
// ws (bf16): Wt [3][64][1024] | Qw [81920][64] | Kw [81920][64] | Vt [256][64][320]
// diag scratch at ws + 128 MB (ws is ~1.34 GB per harness poison size).

// ---------------- Kernel 0: W -> Wt (bf16, [mat][h][k]) ----------------
__global__ __launch_bounds__(256) void wtrans_kernel(
    const float* __restrict__ Wk, const float* __restrict__ Wq,
    const float* __restrict__ Wv, bf16* __restrict__ Wt) {
  __shared__ bf16 tile[64][65];
  const int mat = blockIdx.x >> 4;
  const int kt = (blockIdx.x & 15) << 6;
  const float* __restrict__ W = (mat == 0) ? Wk : ((mat == 1) ? Wq : Wv);
  const int tid = threadIdx.x;
#pragma unroll
  for (int j = 0; j < 16; ++j) {
    const int i = tid + 256 * j;
    const int k = i >> 6, h = i & 63;
    tile[h][k] = (bf16)W[(kt + k) * 64 + h];
  }
  __syncthreads();
#pragma unroll
  for (int j = 0; j < 16; ++j) {
    const int i = tid + 256 * j;
    const int h = i >> 6, k = i & 63;
    Wt[mat * 65536 + h * 1024 + kt + k] = tile[h][k];
  }
}

// ---------------- Kernel 1: QKV projection (R10-best, byte-identical) ----------------
__global__ __launch_bounds__(256) void qkv_kernel(
    const float* __restrict__ x, const bf16* __restrict__ Wt,
    bf16* __restrict__ Qw, bf16* __restrict__ Kw, bf16* __restrict__ Vt) {
  __shared__ __align__(16) bf16 Ws[2][192 * 64];  // 48 KB, XOR-swizzled
  const int tid = threadIdx.x;
  const int w = tid >> 6, l = tid & 63;
  const int lr = l & 15, lg = l >> 4;
  const int m0 = blockIdx.x * 64;
  const int r0 = m0 + 16 * w;

  f32x4 acc[12];
#pragma unroll
  for (int nf = 0; nf < 12; ++nf) acc[nf] = (f32x4)0.0f;

  const char* wsrc[6];
#pragma unroll
  for (int j = 0; j < 6; ++j) {
    const int g = 48 * w + 8 * j + (l >> 3);
    wsrc[j] = (const char*)(Wt + (g >> 6) * 65536 + (g & 63) * 1024) +
              (((l & 7) * 16) ^ ((g & 7) << 4));
  }
  auto wdma = [&](int t) {
    char* lb = (char*)&Ws[t & 1][0];
#pragma unroll
    for (int j = 0; j < 6; ++j)
      GLD16(wsrc[j] + t * 128, lb + (48 * w + 8 * j) * 128);
  };

  const char* xsrc = (const char*)(x + (size_t)(r0 + lr) * 1024) + lg * 32;
  f32x4 gA[4], gB[4];
  auto xload = [&](int t, f32x4* g) {
    const char* p = xsrc + t * 256;
    g[0] = *(const f32x4*)(p);
    g[1] = *(const f32x4*)(p + 16);
    g[2] = *(const f32x4*)(p + 128);
    g[3] = *(const f32x4*)(p + 144);
  };

  wdma(0);
  xload(0, gA);
  xload(1, gB);

  const int sw = (lr & 7) << 4;
  auto step = [&](int t, f32x4* g) {
    if (t < 15) {
      asm volatile("s_waitcnt vmcnt(4)" ::: "memory");
    } else {
      asm volatile("s_waitcnt vmcnt(0)" ::: "memory");
    }
    __builtin_amdgcn_sched_barrier(0);
    __builtin_amdgcn_s_barrier();
    __builtin_amdgcn_sched_barrier(0);

    bf16x8 a0, a1;
#pragma unroll
    for (int i = 0; i < 4; ++i) {
      a0[i] = (bf16)g[0][i]; a0[4 + i] = (bf16)g[1][i];
      a1[i] = (bf16)g[2][i]; a1[4 + i] = (bf16)g[3][i];
    }
    if (t < 15) wdma(t + 1);
    if (t < 14) xload(t + 2, g);

    const char* wb = (const char*)&Ws[t & 1][0];
#pragma unroll
    for (int nf = 0; nf < 12; ++nf) {
      const char* rp = wb + (nf * 16 + lr) * 128;
      const bf16x8 b0 = *(const bf16x8*)(rp + ((lg * 16) ^ sw));
      const bf16x8 b1 = *(const bf16x8*)(rp + ((64 + lg * 16) ^ sw));
      acc[nf] = MFMA16(a0, b0, acc[nf]);
      acc[nf] = MFMA16(a1, b1, acc[nf]);
    }
  };

#pragma unroll
  for (int t2 = 0; t2 < 16; t2 += 2) {
    step(t2, gA);
    step(t2 + 1, gB);
  }

  {
    bf16* Cs = &Ws[0][0];
    asm volatile("s_waitcnt lgkmcnt(0)" ::: "memory");
    __builtin_amdgcn_sched_barrier(0);
    __builtin_amdgcn_s_barrier();
    __builtin_amdgcn_sched_barrier(0);
#pragma unroll
    for (int nf = 0; nf < 12; ++nf) {
      bf16x4 o;
#pragma unroll
      for (int r = 0; r < 4; ++r) o[r] = (bf16)acc[nf][r];
      *(bf16x4*)(Cs + (nf * 16 + lr) * 72 + 16 * w + lg * 4) = o;
    }
    asm volatile("s_waitcnt lgkmcnt(0)" ::: "memory");
    __builtin_amdgcn_sched_barrier(0);
    __builtin_amdgcn_s_barrier();
    __builtin_amdgcn_sched_barrier(0);

    const int i = tid >> 2;
    const int c = tid & 3;
    const int bb = m0 / 320, tt0 = m0 % 320;
    bf16x8 kk0, kk1, qq0, qq1;
#pragma unroll
    for (int s = 0; s < 8; ++s) {
      kk0[s] = Cs[(c * 16 + s) * 72 + i];
      kk1[s] = Cs[(c * 16 + 8 + s) * 72 + i];
      qq0[s] = Cs[(64 + c * 16 + s) * 72 + i];
      qq1[s] = Cs[(64 + c * 16 + 8 + s) * 72 + i];
    }
    *(bf16x8*)(Kw + (size_t)(m0 + i) * 64 + c * 16) = kk0;
    *(bf16x8*)(Kw + (size_t)(m0 + i) * 64 + c * 16 + 8) = kk1;
    *(bf16x8*)(Qw + (size_t)(m0 + i) * 64 + c * 16) = qq0;
    *(bf16x8*)(Qw + (size_t)(m0 + i) * 64 + c * 16 + 8) = qq1;
    const bf16x8 v0 = *(const bf16x8*)(Cs + (128 + i) * 72 + c * 16);
    const bf16x8 v1 = *(const bf16x8*)(Cs + (128 + i) * 72 + c * 16 + 8);
    *(bf16x8*)(Vt + ((size_t)bb * 64 + i) * 320 + tt0 + c * 16) = v0;
    *(bf16x8*)(Vt + ((size_t)bb * 64 + i) * 320 + tt0 + c * 16 + 8) = v1;
  }
}

// ---------------- DIAG A: x read with R10's exact address stream ----------------
// grid 3*1280. Pure reads, max MLP, no LDS/barriers. Visible in rocprof top-5
// iff this pattern runs slower than ~5.3 TB/s.
__global__ __launch_bounds__(256) void xdiagA_kernel(
    const float* __restrict__ x, float* __restrict__ scratch) {
  const int tid = threadIdx.x;
  const int w = tid >> 6, l = tid & 63;
  const int lr = l & 15, lg = l >> 4;
  const int m0 = (blockIdx.x % 1280) * 64;
  const char* xsrc = (const char*)(x + (size_t)(m0 + 16 * w + lr) * 1024) + lg * 32;
  f32x4 s0 = (f32x4)0.0f, s1 = (f32x4)0.0f, s2 = (f32x4)0.0f, s3 = (f32x4)0.0f;
#pragma unroll
  for (int t = 0; t < 16; ++t) {
    const char* p = xsrc + t * 256;
    s0 += *(const f32x4*)(p);
    s1 += *(const f32x4*)(p + 16);
    s2 += *(const f32x4*)(p + 128);
    s3 += *(const f32x4*)(p + 144);
  }
  const f32x4 s = s0 + s1 + s2 + s3;
  scratch[(size_t)blockIdx.x * 256 + tid] = s[0] + s[1] + s[2] + s[3];
}

// ---------------- DIAG B: fully coalesced x read (control) ----------------
// grid 3*1280; block sweeps its 256 KB chunk lane-contiguously.
__global__ __launch_bounds__(256) void xdiagB_kernel(
    const float* __restrict__ x, float* __restrict__ scratch) {
  const int tid = threadIdx.x;
  const float4* p = (const float4*)(x + (size_t)(blockIdx.x % 1280) * 65536);
  float4 s = make_float4(0.f, 0.f, 0.f, 0.f);
#pragma unroll 4
  for (int i = tid; i < 16384; i += 256) {
    const float4 v = p[i];
    s.x += v.x; s.y += v.y; s.z += v.z; s.w += v.w;
  }
  scratch[(size_t)blockIdx.x * 256 + tid] = s.x + s.y + s.z + s.w;
}

// ---------------- Kernel 2: causal attention (frozen, round-6 version) ----------------
template <int QT>
__device__ __forceinline__ void attn_impl(
    int b, const bf16* __restrict__ Qw, const bf16* __restrict__ Kw,
    const bf16* __restrict__ Vt, float* __restrict__ out,
    char* Ks, char* Vs, char* Ps) {
  constexpr int NT = QT + 1;
  const int tid = threadIdx.x;
  const int w = tid >> 6, l = tid & 63;
  const int lr = l & 15, lg = l >> 4;
  const int t0 = QT * 64 + w * 16;
  const int tq = t0 + lr;

  const bf16* qp = Qw + ((size_t)b * 320 + tq) * 64 + lg * 8;
  const bf16x8 bq0 = *(const bf16x8*)qp;
  const bf16x8 bq1 = *(const bf16x8*)(qp + 32);

  f32x4 acc[NT * 4];
#pragma unroll
  for (int i = 0; i < NT * 4; ++i) acc[i] = (f32x4)0.0f;

  bf16x8 kg0, kg1;
  const int krow = w * 16 + (l >> 2);
  const int kcb = (l & 3) * 16;
  const int ksw = (krow & 7) << 4;
  auto gloadK = [&](int st) {
    const bf16* src = Kw + ((size_t)b * 320 + st * 64 + krow) * 64 + (l & 3) * 8;
    kg0 = *(const bf16x8*)src;
    kg1 = *(const bf16x8*)(src + 32);
  };
  auto dswriteK = [&](int buf) {
    char* base = Ks + buf * 8192 + krow * 128;
    *(bf16x8*)(base + (kcb ^ ksw)) = kg0;
    *(bf16x8*)(base + ((kcb + 64) ^ ksw)) = kg1;
  };

  gloadK(0);
  dswriteK(0);
  asm volatile("s_waitcnt lgkmcnt(0)" ::: "memory");
  __builtin_amdgcn_s_barrier();

  const int asw = (lr & 7) << 4;
#pragma unroll
  for (int st = 0; st < NT; ++st) {
    if (st < QT) gloadK(st + 1);
    const char* kb = Ks + (st & 1) * 8192;
#pragma unroll
    for (int nf = 0; nf < 4; ++nf) {
      const char* rp = kb + (nf * 16 + lr) * 128;
      const bf16x8 a0 = *(const bf16x8*)(rp + ((lg * 16) ^ asw));
      const bf16x8 a1 = *(const bf16x8*)(rp + ((64 + lg * 16) ^ asw));
      acc[st * 4 + nf] = MFMA16(a0, bq0, acc[st * 4 + nf]);
      acc[st * 4 + nf] = MFMA16(a1, bq1, acc[st * 4 + nf]);
    }
    if (st < QT) {
      dswriteK((st + 1) & 1);
      asm volatile("s_waitcnt lgkmcnt(0)" ::: "memory");
      __builtin_amdgcn_s_barrier();
    }
  }

  uint2 vg[4];
  const int vrow = w * 16 + (l >> 4);
  auto gloadV = [&](int st) {
    const bf16* src = Vt + ((size_t)b * 64 + vrow) * 320 + st * 64 + (l & 15) * 4;
#pragma unroll
    for (int i = 0; i < 4; ++i) vg[i] = *(const uint2*)(src + i * 4 * 320);
  };
  auto dswriteV = [&](int buf) {
#pragma unroll
    for (int i = 0; i < 4; ++i) {
      const int hl = vrow + i * 4;
      *(uint2*)(Vs + buf * 8192 + hl * 128 + (((l & 15) * 8) ^ ((hl & 7) << 4))) = vg[i];
    }
  };
  gloadV(0);

  float mx = -1e30f;
#pragma unroll
  for (int st = 0; st < NT; ++st)
#pragma unroll
    for (int nf = 0; nf < 4; ++nf)
#pragma unroll
      for (int r = 0; r < 4; ++r) {
        const int sg = st * 64 + nf * 16 + lg * 4 + r;
        float v = acc[st * 4 + nf][r] * 0.03125f;
        v = (sg > tq) ? -1e30f : v;
        acc[st * 4 + nf][r] = v;
        mx = fmaxf(mx, v);
      }
  mx = fmaxf(mx, __shfl_xor(mx, 16));
  mx = fmaxf(mx, __shfl_xor(mx, 32));
  float sum = 0.f;
#pragma unroll
  for (int i = 0; i < NT * 4; ++i)
#pragma unroll
    for (int r = 0; r < 4; ++r) {
      const float p = __expf(acc[i][r] - mx);
      acc[i][r] = p;
      sum += p;
    }
  sum += __shfl_xor(sum, 16);
  sum += __shfl_xor(sum, 32);
  const float rinv = 1.0f / sum;

  dswriteV(0);
  asm volatile("s_waitcnt lgkmcnt(0)" ::: "memory");
  __builtin_amdgcn_s_barrier();

  char* Pw = Ps + w * 2048;
  f32x4 ao[4];
#pragma unroll
  for (int hf = 0; hf < 4; ++hf) ao[hf] = (f32x4)0.0f;

#pragma unroll
  for (int st = 0; st < NT; ++st) {
    if (st < QT) gloadV(st + 1);
#pragma unroll
    for (int nf = 0; nf < 4; ++nf) {
      bf16x4 o;
#pragma unroll
      for (int r = 0; r < 4; ++r) o[r] = (bf16)(acc[st * 4 + nf][r] * rinv);
      *(bf16x4*)(Pw + lr * 128 + ((nf * 32 + lg * 8) ^ asw)) = o;
    }
    const char* vb = Vs + (st & 1) * 8192;
#pragma unroll
    for (int ks = 0; ks < 2; ++ks) {
      const bf16x8 ap = *(const bf16x8*)(Pw + lr * 128 + ((ks * 64 + lg * 16) ^ asw));
#pragma unroll
      for (int hf = 0; hf < 4; ++hf) {
        const bf16x8 bv =
            *(const bf16x8*)(vb + (hf * 16 + lr) * 128 + ((ks * 64 + lg * 16) ^ asw));
        ao[hf] = MFMA16(ap, bv, ao[hf]);
      }
    }
    if (st < QT) {
      dswriteV((st + 1) & 1);
      asm volatile("s_waitcnt lgkmcnt(0)" ::: "memory");
      __builtin_amdgcn_s_barrier();
    }
  }

  const int rowb = t0 + lg * 4;
#pragma unroll
  for (int hf = 0; hf < 4; ++hf)
#pragma unroll
    for (int r = 0; r < 4; ++r)
      out[((size_t)b * 320 + rowb + r) * 64 + hf * 16 + lr] = ao[hf][r];
}

__global__ __launch_bounds__(256) void attn_kernel(
    const bf16* __restrict__ Qw, const bf16* __restrict__ Kw,
    const bf16* __restrict__ Vt, float* __restrict__ out) {
  __shared__ __align__(16) char Ks[2 * 8192];
  __shared__ __align__(16) char Vs[2 * 8192];
  __shared__ __align__(16) char Ps[4 * 2048];
  const int b = blockIdx.x;
  const int qt = 4 - blockIdx.y;
  switch (qt) {
    case 0: attn_impl<0>(b, Qw, Kw, Vt, out, Ks, Vs, Ps); break;
    case 1: attn_impl<1>(b, Qw, Kw, Vt, out, Ks, Vs, Ps); break;
    case 2: attn_impl<2>(b, Qw, Kw, Vt, out, Ks, Vs, Ps); break;
    case 3: attn_impl<3>(b, Qw, Kw, Vt, out, Ks, Vs, Ps); break;
    default: attn_impl<4>(b, Qw, Kw, Vt, out, Ks, Vs, Ps); break;
  }
}

extern "C" void kernel_launch(void* const* d_in, const int* in_sizes, int n_in,
                              void* d_out, int out_size, void* d_ws, size_t ws_size,
                              hipStream_t stream) {
  const float* x  = (const float*)d_in[0];
  const float* Wk = (const float*)d_in[1];
  const float* Wq = (const float*)d_in[2];
  const float* Wv = (const float*)d_in[3];
  float* out = (float*)d_out;

  bf16* Wt = (bf16*)d_ws;
  bf16* Qw = Wt + 3 * 64 * 1024;
  bf16* Kw = Qw + (size_t)81920 * 64;
  bf16* Vt = Kw + (size_t)81920 * 64;
  float* scratch = (float*)((char*)d_ws + (size_t)128 * 1024 * 1024);  // far scratch

  hipLaunchKernelGGL(wtrans_kernel, dim3(48), dim3(256), 0, stream, Wk, Wq, Wv, Wt);
  hipLaunchKernelGGL(qkv_kernel, dim3(1280), dim3(256), 0, stream, x, Wt, Qw, Kw, Vt);
  hipLaunchKernelGGL(attn_kernel, dim3(256, 5), dim3(256), 0, stream, Qw, Kw, Vt, out);
  // MEASUREMENT: pure x-read diagnostics (deterministic, write to far scratch).
  // Visible in top-5 iff slower than ~5.3 TB/s (3 reps of 335 MB vs 190us wall).
  hipLaunchKernelGGL(xdiagA_kernel, dim3(3 * 1280), dim3(256), 0, stream, x, scratch);
  hipLaunchKernelGGL(xdiagB_kernel, dim3(3 * 1280), dim3(256), 0, stream, x,
                     scratch + (size_t)3 * 1280 * 256);
}

// Round 18
// 113.625 us; speedup vs baseline: 3.6978x; 3.6978x over previous
//
#include <hip/hip_runtime.h>

typedef __bf16 bf16;
typedef __bf16 bf16x4 __attribute__((ext_vector_type(4)));
typedef __bf16 bf16x8 __attribute__((ext_vector_type(8)));
typedef float f32x4 __attribute__((ext_vector_type(4)));

#define MFMA16(a, b, c) __builtin_amdgcn_mfma_f32_16x16x32_bf16((a), (b), (c), 0, 0, 0)

// global -> LDS DMA, 16B per lane; LDS dest is wave-uniform base + lane*16.
#define GLD16(gp, lp)                                                              \
  __builtin_amdgcn_global_load_lds(                                                \
      (const __attribute__((address_space(1))) unsigned int*)(unsigned long long)(gp), \
      (__attribute__((address_space(3))) unsigned int*)(unsigned long long)(lp), 16, 0, 0)

// B=256, T=320, C=1024, H=64;  M = B*T = 81920
// ws (bf16): Wt [3][64][1024] | Qw [81920][64] | Kw [81920][64] | Vt [256][64][320]

// ---------------- Kernel 0: W -> Wt (bf16, [mat][h][k]) ----------------
__global__ __launch_bounds__(256) void wtrans_kernel(
    const float* __restrict__ Wk, const float* __restrict__ Wq,
    const float* __restrict__ Wv, bf16* __restrict__ Wt) {
  __shared__ bf16 tile[64][65];
  const int mat = blockIdx.x >> 4;
  const int kt = (blockIdx.x & 15) << 6;
  const float* __restrict__ W = (mat == 0) ? Wk : ((mat == 1) ? Wq : Wv);
  const int tid = threadIdx.x;
#pragma unroll
  for (int j = 0; j < 16; ++j) {
    const int i = tid + 256 * j;
    const int k = i >> 6, h = i & 63;
    tile[h][k] = (bf16)W[(kt + k) * 64 + h];
  }
  __syncthreads();
#pragma unroll
  for (int j = 0; j < 16; ++j) {
    const int i = tid + 256 * j;
    const int h = i >> 6, k = i & 63;
    Wt[mat * 65536 + h * 1024 + kt + k] = tile[h][k];
  }
}

// ---------------- Kernel 1: QKV projection (R10-best, byte-identical) ----------------
__global__ __launch_bounds__(256) void qkv_kernel(
    const float* __restrict__ x, const bf16* __restrict__ Wt,
    bf16* __restrict__ Qw, bf16* __restrict__ Kw, bf16* __restrict__ Vt) {
  __shared__ __align__(16) bf16 Ws[2][192 * 64];  // 48 KB, XOR-swizzled
  const int tid = threadIdx.x;
  const int w = tid >> 6, l = tid & 63;
  const int lr = l & 15, lg = l >> 4;
  const int m0 = blockIdx.x * 64;
  const int r0 = m0 + 16 * w;

  f32x4 acc[12];
#pragma unroll
  for (int nf = 0; nf < 12; ++nf) acc[nf] = (f32x4)0.0f;

  const char* wsrc[6];
#pragma unroll
  for (int j = 0; j < 6; ++j) {
    const int g = 48 * w + 8 * j + (l >> 3);
    wsrc[j] = (const char*)(Wt + (g >> 6) * 65536 + (g & 63) * 1024) +
              (((l & 7) * 16) ^ ((g & 7) << 4));
  }
  auto wdma = [&](int t) {
    char* lb = (char*)&Ws[t & 1][0];
#pragma unroll
    for (int j = 0; j < 6; ++j)
      GLD16(wsrc[j] + t * 128, lb + (48 * w + 8 * j) * 128);
  };

  const char* xsrc = (const char*)(x + (size_t)(r0 + lr) * 1024) + lg * 32;
  f32x4 gA[4], gB[4];
  auto xload = [&](int t, f32x4* g) {
    const char* p = xsrc + t * 256;
    g[0] = *(const f32x4*)(p);
    g[1] = *(const f32x4*)(p + 16);
    g[2] = *(const f32x4*)(p + 128);
    g[3] = *(const f32x4*)(p + 144);
  };

  wdma(0);
  xload(0, gA);
  xload(1, gB);

  const int sw = (lr & 7) << 4;
  auto step = [&](int t, f32x4* g) {
    if (t < 15) {
      asm volatile("s_waitcnt vmcnt(4)" ::: "memory");
    } else {
      asm volatile("s_waitcnt vmcnt(0)" ::: "memory");
    }
    __builtin_amdgcn_sched_barrier(0);
    __builtin_amdgcn_s_barrier();
    __builtin_amdgcn_sched_barrier(0);

    bf16x8 a0, a1;
#pragma unroll
    for (int i = 0; i < 4; ++i) {
      a0[i] = (bf16)g[0][i]; a0[4 + i] = (bf16)g[1][i];
      a1[i] = (bf16)g[2][i]; a1[4 + i] = (bf16)g[3][i];
    }
    if (t < 15) wdma(t + 1);
    if (t < 14) xload(t + 2, g);

    const char* wb = (const char*)&Ws[t & 1][0];
#pragma unroll
    for (int nf = 0; nf < 12; ++nf) {
      const char* rp = wb + (nf * 16 + lr) * 128;
      const bf16x8 b0 = *(const bf16x8*)(rp + ((lg * 16) ^ sw));
      const bf16x8 b1 = *(const bf16x8*)(rp + ((64 + lg * 16) ^ sw));
      acc[nf] = MFMA16(a0, b0, acc[nf]);
      acc[nf] = MFMA16(a1, b1, acc[nf]);
    }
  };

#pragma unroll
  for (int t2 = 0; t2 < 16; t2 += 2) {
    step(t2, gA);
    step(t2 + 1, gB);
  }

  {
    bf16* Cs = &Ws[0][0];
    asm volatile("s_waitcnt lgkmcnt(0)" ::: "memory");
    __builtin_amdgcn_sched_barrier(0);
    __builtin_amdgcn_s_barrier();
    __builtin_amdgcn_sched_barrier(0);
#pragma unroll
    for (int nf = 0; nf < 12; ++nf) {
      bf16x4 o;
#pragma unroll
      for (int r = 0; r < 4; ++r) o[r] = (bf16)acc[nf][r];
      *(bf16x4*)(Cs + (nf * 16 + lr) * 72 + 16 * w + lg * 4) = o;
    }
    asm volatile("s_waitcnt lgkmcnt(0)" ::: "memory");
    __builtin_amdgcn_sched_barrier(0);
    __builtin_amdgcn_s_barrier();
    __builtin_amdgcn_sched_barrier(0);

    const int i = tid >> 2;
    const int c = tid & 3;
    const int bb = m0 / 320, tt0 = m0 % 320;
    bf16x8 kk0, kk1, qq0, qq1;
#pragma unroll
    for (int s = 0; s < 8; ++s) {
      kk0[s] = Cs[(c * 16 + s) * 72 + i];
      kk1[s] = Cs[(c * 16 + 8 + s) * 72 + i];
      qq0[s] = Cs[(64 + c * 16 + s) * 72 + i];
      qq1[s] = Cs[(64 + c * 16 + 8 + s) * 72 + i];
    }
    *(bf16x8*)(Kw + (size_t)(m0 + i) * 64 + c * 16) = kk0;
    *(bf16x8*)(Kw + (size_t)(m0 + i) * 64 + c * 16 + 8) = kk1;
    *(bf16x8*)(Qw + (size_t)(m0 + i) * 64 + c * 16) = qq0;
    *(bf16x8*)(Qw + (size_t)(m0 + i) * 64 + c * 16 + 8) = qq1;
    const bf16x8 v0 = *(const bf16x8*)(Cs + (128 + i) * 72 + c * 16);
    const bf16x8 v1 = *(const bf16x8*)(Cs + (128 + i) * 72 + c * 16 + 8);
    *(bf16x8*)(Vt + ((size_t)bb * 64 + i) * 320 + tt0 + c * 16) = v0;
    *(bf16x8*)(Vt + ((size_t)bb * 64 + i) * 320 + tt0 + c * 16 + 8) = v1;
  }
}

// ---------------- Kernel 2: causal attention, static per-(QT,W) causal trim ----------------
// Wave W needs score frags f < FMAX = 4*QT+W+1 (rest are exp(-inf)=0: skipping
// + zero-filling <=1 P slot is bit-identical). Fully static via <QT,W> (R4's
// runtime-break codegen trap avoided). Staging/barrier structure identical
// across waves (all waves hit all barriers).
template <int QT, int W>
__device__ __forceinline__ void attn_core(
    int b, const bf16* __restrict__ Qw, const bf16* __restrict__ Kw,
    const bf16* __restrict__ Vt, float* __restrict__ out,
    char* Ks, char* Vs, char* Ps) {
  constexpr int NT = QT + 1;           // 64-wide s-tiles
  constexpr int FMAX = 4 * QT + W + 1; // computed score frags for this wave
  constexpr int KSL = (W + 2) / 2;     // last-tile PV k-steps (1 or 2)
  const int tid = threadIdx.x;
  const int l = tid & 63;
  const int lr = l & 15, lg = l >> 4;
  const int t0 = QT * 64 + W * 16;
  const int tq = t0 + lr;

  const bf16* qp = Qw + ((size_t)b * 320 + tq) * 64 + lg * 8;
  const bf16x8 bq0 = *(const bf16x8*)qp;
  const bf16x8 bq1 = *(const bf16x8*)(qp + 32);

  f32x4 acc[FMAX];
#pragma unroll
  for (int i = 0; i < FMAX; ++i) acc[i] = (f32x4)0.0f;

  bf16x8 kg0, kg1;
  const int krow = W * 16 + (l >> 2);
  const int kcb = (l & 3) * 16;
  const int ksw = (krow & 7) << 4;
  auto gloadK = [&](int st) {
    const bf16* src = Kw + ((size_t)b * 320 + st * 64 + krow) * 64 + (l & 3) * 8;
    kg0 = *(const bf16x8*)src;
    kg1 = *(const bf16x8*)(src + 32);
  };
  auto dswriteK = [&](int buf) {
    char* base = Ks + buf * 8192 + krow * 128;
    *(bf16x8*)(base + (kcb ^ ksw)) = kg0;
    *(bf16x8*)(base + ((kcb + 64) ^ ksw)) = kg1;
  };

  gloadK(0);
  dswriteK(0);
  asm volatile("s_waitcnt lgkmcnt(0)" ::: "memory");
  __builtin_amdgcn_s_barrier();

  const int asw = (lr & 7) << 4;
#pragma unroll
  for (int st = 0; st < NT; ++st) {
    if (st < QT) gloadK(st + 1);
    const char* kb = Ks + (st & 1) * 8192;
#pragma unroll
    for (int nf = 0; nf < 4; ++nf) {
      if (st * 4 + nf >= FMAX) break;  // compile-time bound (st, nf static)
      const char* rp = kb + (nf * 16 + lr) * 128;
      const bf16x8 a0 = *(const bf16x8*)(rp + ((lg * 16) ^ asw));
      const bf16x8 a1 = *(const bf16x8*)(rp + ((64 + lg * 16) ^ asw));
      acc[st * 4 + nf] = MFMA16(a0, bq0, acc[st * 4 + nf]);
      acc[st * 4 + nf] = MFMA16(a1, bq1, acc[st * 4 + nf]);
    }
    if (st < QT) {
      dswriteK((st + 1) & 1);
      asm volatile("s_waitcnt lgkmcnt(0)" ::: "memory");
      __builtin_amdgcn_s_barrier();
    }
  }

  uint2 vg[4];
  const int vrow = W * 16 + (l >> 4);
  auto gloadV = [&](int st) {
    const bf16* src = Vt + ((size_t)b * 64 + vrow) * 320 + st * 64 + (l & 15) * 4;
#pragma unroll
    for (int i = 0; i < 4; ++i) vg[i] = *(const uint2*)(src + i * 4 * 320);
  };
  auto dswriteV = [&](int buf) {
#pragma unroll
    for (int i = 0; i < 4; ++i) {
      const int hl = vrow + i * 4;
      *(uint2*)(Vs + buf * 8192 + hl * 128 + (((l & 15) * 8) ^ ((hl & 7) << 4))) = vg[i];
    }
  };
  gloadV(0);

  float mx = -1e30f;
#pragma unroll
  for (int f = 0; f < FMAX; ++f)
#pragma unroll
    for (int r = 0; r < 4; ++r) {
      const int sg = f * 16 + lg * 4 + r;
      float v = acc[f][r] * 0.03125f;
      v = (sg > tq) ? -1e30f : v;
      acc[f][r] = v;
      mx = fmaxf(mx, v);
    }
  mx = fmaxf(mx, __shfl_xor(mx, 16));
  mx = fmaxf(mx, __shfl_xor(mx, 32));
  float sum = 0.f;
#pragma unroll
  for (int f = 0; f < FMAX; ++f)
#pragma unroll
    for (int r = 0; r < 4; ++r) {
      const float p = __expf(acc[f][r] - mx);
      acc[f][r] = p;
      sum += p;
    }
  sum += __shfl_xor(sum, 16);
  sum += __shfl_xor(sum, 32);
  const float rinv = 1.0f / sum;

  dswriteV(0);
  asm volatile("s_waitcnt lgkmcnt(0)" ::: "memory");
  __builtin_amdgcn_s_barrier();

  char* Pw = Ps + W * 2048;
  f32x4 ao[4];
#pragma unroll
  for (int hf = 0; hf < 4; ++hf) ao[hf] = (f32x4)0.0f;

#pragma unroll
  for (int st = 0; st < NT; ++st) {
    if (st < QT) gloadV(st + 1);
#pragma unroll
    for (int nf = 0; nf < 4; ++nf) {
      if (st * 4 + nf >= FMAX) break;  // static
      bf16x4 o;
#pragma unroll
      for (int r = 0; r < 4; ++r) o[r] = (bf16)(acc[st * 4 + nf][r] * rinv);
      *(bf16x4*)(Pw + lr * 128 + ((nf * 32 + lg * 8) ^ asw)) = o;
    }
    if (st == QT && (W & 1) == 0) {  // zero-fill the one consumed-but-trimmed frag
      bf16x4 z;
      z[0] = z[1] = z[2] = z[3] = (bf16)0.0f;
      *(bf16x4*)(Pw + lr * 128 + (((W + 1) * 32 + lg * 8) ^ asw)) = z;
    }
    const char* vb = Vs + (st & 1) * 8192;
#pragma unroll
    for (int ks = 0; ks < 2; ++ks) {
      if (st == QT && ks >= KSL) break;  // static: trim last-tile PV k-steps
      const bf16x8 ap = *(const bf16x8*)(Pw + lr * 128 + ((ks * 64 + lg * 16) ^ asw));
#pragma unroll
      for (int hf = 0; hf < 4; ++hf) {
        const bf16x8 bv =
            *(const bf16x8*)(vb + (hf * 16 + lr) * 128 + ((ks * 64 + lg * 16) ^ asw));
        ao[hf] = MFMA16(ap, bv, ao[hf]);
      }
    }
    if (st < QT) {
      dswriteV((st + 1) & 1);
      asm volatile("s_waitcnt lgkmcnt(0)" ::: "memory");
      __builtin_amdgcn_s_barrier();
    }
  }

  const int rowb = t0 + lg * 4;
#pragma unroll
  for (int hf = 0; hf < 4; ++hf)
#pragma unroll
    for (int r = 0; r < 4; ++r)
      out[((size_t)b * 320 + rowb + r) * 64 + hf * 16 + lr] = ao[hf][r];
}

template <int QT>
__device__ __forceinline__ void attn_disp(
    int b, int w, const bf16* __restrict__ Qw, const bf16* __restrict__ Kw,
    const bf16* __restrict__ Vt, float* __restrict__ out,
    char* Ks, char* Vs, char* Ps) {
  switch (w) {
    case 0: attn_core<QT, 0>(b, Qw, Kw, Vt, out, Ks, Vs, Ps); break;
    case 1: attn_core<QT, 1>(b, Qw, Kw, Vt, out, Ks, Vs, Ps); break;
    case 2: attn_core<QT, 2>(b, Qw, Kw, Vt, out, Ks, Vs, Ps); break;
    default: attn_core<QT, 3>(b, Qw, Kw, Vt, out, Ks, Vs, Ps); break;
  }
}

__global__ __launch_bounds__(256) void attn_kernel(
    const bf16* __restrict__ Qw, const bf16* __restrict__ Kw,
    const bf16* __restrict__ Vt, float* __restrict__ out) {
  __shared__ __align__(16) char Ks[2 * 8192];
  __shared__ __align__(16) char Vs[2 * 8192];
  __shared__ __align__(16) char Ps[4 * 2048];
  const int b = blockIdx.x;
  const int qt = 4 - blockIdx.y;  // heavy blocks dispatch first
  const int w = threadIdx.x >> 6; // wave-uniform
  switch (qt) {
    case 0: attn_disp<0>(b, w, Qw, Kw, Vt, out, Ks, Vs, Ps); break;
    case 1: attn_disp<1>(b, w, Qw, Kw, Vt, out, Ks, Vs, Ps); break;
    case 2: attn_disp<2>(b, w, Qw, Kw, Vt, out, Ks, Vs, Ps); break;
    case 3: attn_disp<3>(b, w, Qw, Kw, Vt, out, Ks, Vs, Ps); break;
    default: attn_disp<4>(b, w, Qw, Kw, Vt, out, Ks, Vs, Ps); break;
  }
}

extern "C" void kernel_launch(void* const* d_in, const int* in_sizes, int n_in,
                              void* d_out, int out_size, void* d_ws, size_t ws_size,
                              hipStream_t stream) {
  const float* x  = (const float*)d_in[0];
  const float* Wk = (const float*)d_in[1];
  const float* Wq = (const float*)d_in[2];
  const float* Wv = (const float*)d_in[3];
  float* out = (float*)d_out;

  bf16* Wt = (bf16*)d_ws;
  bf16* Qw = Wt + 3 * 64 * 1024;
  bf16* Kw = Qw + (size_t)81920 * 64;
  bf16* Vt = Kw + (size_t)81920 * 64;

  hipLaunchKernelGGL(wtrans_kernel, dim3(48), dim3(256), 0, stream, Wk, Wq, Wv, Wt);
  hipLaunchKernelGGL(qkv_kernel, dim3(1280), dim3(256), 0, stream, x, Wt, Qw, Kw, Vt);
  hipLaunchKernelGGL(attn_kernel, dim3(256, 5), dim3(256), 0, stream, Qw, Kw, Vt, out);
}